// Round 8
// baseline (130.024 us; speedup 1.0000x reference)
//
#include <hip/hip_runtime.h>
#include <hip/hip_bf16.h>
#include <math.h>

// Problem constants (from reference setup_inputs)
constexpr int B_  = 8;
constexpr int CIN = 3;
constexpr int C_  = 64;
constexpr int H_  = 256;
constexpr int W_  = 256;
constexpr int TAPS = 9;   // K*K, K=3

typedef float f32x4 __attribute__((ext_vector_type(4)));

// ============================================================================
// Kernel 1 (compute-bound): kern[b][y][t][x] = conv1x1(relu(conv3x3(lr)))
// ============================================================================
__global__ __launch_bounds__(256, 4)
void hsa_kern(const float* __restrict__ lr,
              const float* __restrict__ w1,
              const float* __restrict__ b1,
              const float* __restrict__ w2,
              const float* __restrict__ b2,
              float* __restrict__ kws)
{
    __shared__ float w2t[C_][12];       // transposed 1x1 weights

    const int tid = threadIdx.x;
    const int blk = blockIdx.x;         // 0 .. B_*H_-1
    const int b = blk / H_;
    const int y = blk % H_;

    for (int i = tid; i < TAPS * C_; i += 256) {
        const int t = i / C_;
        const int c = i % C_;
        w2t[c][t] = w2[i];
    }
    __syncthreads();

    const int x = tid;                  // 0..255
    float win[CIN][3][3];
    #pragma unroll
    for (int ci = 0; ci < CIN; ++ci) {
        #pragma unroll
        for (int r = 0; r < 3; ++r) {
            const int yy = y + r - 1;
            const bool vy = (unsigned)yy < (unsigned)H_;
            const float* row = lr + ((size_t)(b * CIN + ci) * H_ + yy) * W_;
            win[ci][r][0] = (vy && x > 0)       ? row[x - 1] : 0.f;
            win[ci][r][1] = vy                   ? row[x]     : 0.f;
            win[ci][r][2] = (vy && x < W_ - 1)  ? row[x + 1] : 0.f;
        }
    }

    float acc[TAPS];
    #pragma unroll
    for (int t = 0; t < TAPS; ++t) acc[t] = b2[t];

    for (int c = 0; c < C_; ++c) {
        const float* wc = w1 + c * 27;
        float h0 = b1[c], h1 = 0.f, h2 = 0.f;
        #pragma unroll
        for (int r = 0; r < 3; ++r)
            #pragma unroll
            for (int j = 0; j < 3; ++j) {
                h0 = fmaf(wc[(0 * 3 + r) * 3 + j], win[0][r][j], h0);
                h1 = fmaf(wc[(1 * 3 + r) * 3 + j], win[1][r][j], h1);
                h2 = fmaf(wc[(2 * 3 + r) * 3 + j], win[2][r][j], h2);
            }
        const float hsum = fmaxf((h0 + h1) + h2, 0.f);   // ReLU

        const float4 wa = *(const float4*)&w2t[c][0];
        const float4 wb = *(const float4*)&w2t[c][4];
        const float  w8 = w2t[c][8];
        acc[0] = fmaf(wa.x, hsum, acc[0]);
        acc[1] = fmaf(wa.y, hsum, acc[1]);
        acc[2] = fmaf(wa.z, hsum, acc[2]);
        acc[3] = fmaf(wa.w, hsum, acc[3]);
        acc[4] = fmaf(wb.x, hsum, acc[4]);
        acc[5] = fmaf(wb.y, hsum, acc[5]);
        acc[6] = fmaf(wb.z, hsum, acc[6]);
        acc[7] = fmaf(wb.w, hsum, acc[7]);
        acc[8] = fmaf(w8,  hsum, acc[8]);
    }

    float* kr = kws + (size_t)(b * H_ + y) * TAPS * W_;
    #pragma unroll
    for (int t = 0; t < TAPS; ++t) kr[t * W_ + x] = acc[t];
}

// ============================================================================
// Kernel 2 (memory-bound): out = h * sigmoid(sum_taps shifted(h) * kern)
// Block = (b,y) row (XCD-swizzled), wave w owns channels [16w,16w+16).
// NO LDS, NO barrier, NO shuffles:
//  - column halo loaded directly (center float4 + left/right scalar, clamped)
//  - ALL boundary masking (y rows + lane-edge columns) folded into kt taps
//    once per wave -> per-channel compute is pure FMA.
//  - explicit 2-pair register pipeline; asm "+v" fences after each pair-load
//    pin the loads at their issue point (R7's pipeline was sunk by the
//    scheduler: VGPR_Count 52 proved buffers never co-resident).
// ============================================================================
struct ChBuf {
    f32x4 cA, cB, cC;        // center rows y-1, y, y+1
    float lA, lB, lC;        // x0-1 column
    float rA, rB, rC;        // x0+4 column
};

#define PIN(bf) asm volatile("" : "+v"((bf).cA), "+v"((bf).cB), "+v"((bf).cC), \
    "+v"((bf).lA), "+v"((bf).lB), "+v"((bf).lC),                               \
    "+v"((bf).rA), "+v"((bf).rB), "+v"((bf).rC))

__global__ __launch_bounds__(256, 3)
void hsa_gate(const float* __restrict__ hin,
              const float* __restrict__ kws,
              float* __restrict__ out)
{
    const int tid = threadIdx.x;
    const int bid = blockIdx.x;
    // bijective XCD swizzle: 2048 blocks = 8 XCDs x 256
    const int nb  = (bid & 7) * (B_ * H_ / 8) + (bid >> 3);
    const int b = nb / H_;
    const int y = nb % H_;

    const int lane = tid & 63;
    const int wav  = tid >> 6;
    const int x0   = lane * 4;
    const int cbase = wav * 16;

    const int ym1 = (y > 0) ? (y - 1) : 0;
    const int yp1 = (y < H_ - 1) ? (y + 1) : (H_ - 1);
    const size_t rb0 = (size_t)ym1 * W_;     // row bases (no x)
    const size_t rb1 = (size_t)y   * W_;
    const size_t rb2 = (size_t)yp1 * W_;
    const int lx = (x0 > 0) ? (x0 - 1) : 0;          // clamped, masked via kt
    const int rx = (x0 + 4 < W_) ? (x0 + 4) : (W_ - 1);

    const float* hb = hin + (size_t)b * C_ * H_ * W_;
    const size_t plane = (size_t)H_ * W_;

    // ---- kt: 9 taps straight from global (issued first, deepest in flight) --
    const float* kr = kws + (size_t)(b * H_ + y) * TAPS * W_;
    f32x4 kt[TAPS];
    #pragma unroll
    for (int t = 0; t < TAPS; ++t) kt[t] = *(const f32x4*)(kr + t * W_ + x0);

    auto load_ch = [&](ChBuf& bf, int c) {
        const float* q = hb + (size_t)(cbase + c) * plane;
        bf.cA = *(const f32x4*)(q + rb0 + x0);
        bf.cB = *(const f32x4*)(q + rb1 + x0);
        bf.cC = *(const f32x4*)(q + rb2 + x0);
        bf.lA = q[rb0 + lx];  bf.lB = q[rb1 + lx];  bf.lC = q[rb2 + lx];
        bf.rA = q[rb0 + rx];  bf.rB = q[rb1 + rx];  bf.rC = q[rb2 + rx];
    };

    // ---- prologue: 2 pairs (4 channels) issued before any compute ----
    ChBuf A0, A1, B0, B1;
    load_ch(A0, 0); load_ch(A1, 1); PIN(A0); PIN(A1);
    load_ch(B0, 2); load_ch(B1, 3); PIN(B0); PIN(B1);

    // ---- fold ALL boundary masks into kt (once per wave) ----
    const float mask0 = (y > 0)      ? 1.f : 0.f;
    const float mask2 = (y < H_ - 1) ? 1.f : 0.f;
    const float lmask = (x0 > 0)     ? 1.f : 0.f;
    const float rmask = (x0 + 4 < W_) ? 1.f : 0.f;
    kt[0] *= mask0; kt[1] *= mask0; kt[2] *= mask0;
    kt[6] *= mask2; kt[7] *= mask2; kt[8] *= mask2;
    kt[0].x *= lmask; kt[3].x *= lmask; kt[6].x *= lmask;
    kt[2].w *= rmask; kt[5].w *= rmask; kt[8].w *= rmask;

    float* ob = out + ((size_t)b * C_ * H_ + (size_t)y) * W_ + x0;

    auto gate_ch = [&](const ChBuf& bf, int c) {
        float sim0 = 0.f, sim1 = 0.f, sim2 = 0.f, sim3 = 0.f;
        #pragma unroll
        for (int r = 0; r < 3; ++r) {
            const f32x4 cv = (r == 0) ? bf.cA : (r == 1) ? bf.cB : bf.cC;
            const float w0 = (r == 0) ? bf.lA : (r == 1) ? bf.lB : bf.lC;
            const float w5 = (r == 0) ? bf.rA : (r == 1) ? bf.rB : bf.rC;
            const f32x4 k0 = kt[r * 3 + 0];
            const f32x4 k1 = kt[r * 3 + 1];
            const f32x4 k2 = kt[r * 3 + 2];
            sim0 = fmaf(w0,   k0.x, sim0); sim1 = fmaf(cv.x, k0.y, sim1);
            sim2 = fmaf(cv.y, k0.z, sim2); sim3 = fmaf(cv.z, k0.w, sim3);
            sim0 = fmaf(cv.x, k1.x, sim0); sim1 = fmaf(cv.y, k1.y, sim1);
            sim2 = fmaf(cv.z, k1.z, sim2); sim3 = fmaf(cv.w, k1.w, sim3);
            sim0 = fmaf(cv.y, k2.x, sim0); sim1 = fmaf(cv.z, k2.y, sim1);
            sim2 = fmaf(cv.w, k2.z, sim2); sim3 = fmaf(w5,   k2.w, sim3);
        }
        f32x4 o;
        o.x = bf.cB.x * __builtin_amdgcn_rcpf(1.f + __expf(-sim0));
        o.y = bf.cB.y * __builtin_amdgcn_rcpf(1.f + __expf(-sim1));
        o.z = bf.cB.z * __builtin_amdgcn_rcpf(1.f + __expf(-sim2));
        o.w = bf.cB.w * __builtin_amdgcn_rcpf(1.f + __expf(-sim3));
        *(f32x4*)(ob + (size_t)(cbase + c) * plane) = o;
    };

    // ---- steady state: compute one pair while the other pair's 18 loads fly
    #pragma unroll
    for (int p = 0; p < 8; ++p) {
        ChBuf& u0 = (p & 1) ? B0 : A0;
        ChBuf& u1 = (p & 1) ? B1 : A1;
        gate_ch(u0, 2 * p);
        gate_ch(u1, 2 * p + 1);
        if (p + 2 < 8) {
            load_ch(u0, 2 * (p + 2));
            load_ch(u1, 2 * (p + 2) + 1);
            PIN(u0); PIN(u1);
        }
    }
}

// ============================================================================
// Fallback: single fused kernel (used only if ws_size is too small)
// ============================================================================
__global__ __launch_bounds__(256, 4)
void hsa_fused(const float* __restrict__ lr,
               const float* __restrict__ hin,
               const float* __restrict__ w1,
               const float* __restrict__ b1,
               const float* __restrict__ w2,
               const float* __restrict__ b2,
               float* __restrict__ out)
{
    __shared__ float kernS[TAPS][W_];
    __shared__ float w2t[C_][12];

    const int tid = threadIdx.x;
    const int blk = blockIdx.x;
    const int b = blk / H_;
    const int y = blk % H_;

    for (int i = tid; i < TAPS * C_; i += 256) {
        const int t = i / C_;
        const int c = i % C_;
        w2t[c][t] = w2[i];
    }
    __syncthreads();

    {
        const int x = tid;
        float win[CIN][3][3];
        #pragma unroll
        for (int ci = 0; ci < CIN; ++ci)
            #pragma unroll
            for (int r = 0; r < 3; ++r) {
                const int yy = y + r - 1;
                const bool vy = (unsigned)yy < (unsigned)H_;
                const float* row = lr + ((size_t)(b * CIN + ci) * H_ + yy) * W_;
                win[ci][r][0] = (vy && x > 0)      ? row[x - 1] : 0.f;
                win[ci][r][1] = vy                  ? row[x]     : 0.f;
                win[ci][r][2] = (vy && x < W_ - 1) ? row[x + 1] : 0.f;
            }

        float acc[TAPS];
        #pragma unroll
        for (int t = 0; t < TAPS; ++t) acc[t] = b2[t];

        for (int c = 0; c < C_; ++c) {
            const float* wc = w1 + c * 27;
            float h0 = b1[c], h1 = 0.f, h2 = 0.f;
            #pragma unroll
            for (int r = 0; r < 3; ++r)
                #pragma unroll
                for (int j = 0; j < 3; ++j) {
                    h0 = fmaf(wc[(0 * 3 + r) * 3 + j], win[0][r][j], h0);
                    h1 = fmaf(wc[(1 * 3 + r) * 3 + j], win[1][r][j], h1);
                    h2 = fmaf(wc[(2 * 3 + r) * 3 + j], win[2][r][j], h2);
                }
            const float hsum = fmaxf((h0 + h1) + h2, 0.f);
            const float4 wa = *(const float4*)&w2t[c][0];
            const float4 wb = *(const float4*)&w2t[c][4];
            const float  w8 = w2t[c][8];
            acc[0] = fmaf(wa.x, hsum, acc[0]);
            acc[1] = fmaf(wa.y, hsum, acc[1]);
            acc[2] = fmaf(wa.z, hsum, acc[2]);
            acc[3] = fmaf(wa.w, hsum, acc[3]);
            acc[4] = fmaf(wb.x, hsum, acc[4]);
            acc[5] = fmaf(wb.y, hsum, acc[5]);
            acc[6] = fmaf(wb.z, hsum, acc[6]);
            acc[7] = fmaf(wb.w, hsum, acc[7]);
            acc[8] = fmaf(w8,  hsum, acc[8]);
        }
        #pragma unroll
        for (int t = 0; t < TAPS; ++t) kernS[t][x] = acc[t];
    }
    __syncthreads();

    const int lane = tid & 63;
    const int wav  = tid >> 6;
    const int x0   = lane * 4;

    float4 kt[TAPS];
    #pragma unroll
    for (int t = 0; t < TAPS; ++t) kt[t] = *(const float4*)&kernS[t][x0];

    #pragma unroll 4
    for (int cc = 0; cc < 16; ++cc) {
        const int c = wav * 16 + cc;
        const float* hb = hin + (size_t)(b * C_ + c) * H_ * W_;

        float4 rowv[3];
        float  lft[3], rgt[3];
        #pragma unroll
        for (int r = 0; r < 3; ++r) {
            const int yy = y + r - 1;
            const bool vy = (unsigned)yy < (unsigned)H_;
            float4 m;
            if (vy) m = *(const float4*)(hb + (size_t)yy * W_ + x0);
            else    m = make_float4(0.f, 0.f, 0.f, 0.f);
            rowv[r] = m;
            float l  = __shfl_up(m.w, 1);
            float rr = __shfl_down(m.x, 1);
            if (lane == 0)  l  = 0.f;
            if (lane == 63) rr = 0.f;
            lft[r] = l; rgt[r] = rr;
        }

        float sim0 = 0.f, sim1 = 0.f, sim2 = 0.f, sim3 = 0.f;
        #pragma unroll
        for (int r = 0; r < 3; ++r) {
            const float w6_0 = lft[r];
            const float w6_1 = rowv[r].x;
            const float w6_2 = rowv[r].y;
            const float w6_3 = rowv[r].z;
            const float w6_4 = rowv[r].w;
            const float w6_5 = rgt[r];
            { const float4 k4 = kt[r*3+0];
              sim0 = fmaf(w6_0, k4.x, sim0); sim1 = fmaf(w6_1, k4.y, sim1);
              sim2 = fmaf(w6_2, k4.z, sim2); sim3 = fmaf(w6_3, k4.w, sim3); }
            { const float4 k4 = kt[r*3+1];
              sim0 = fmaf(w6_1, k4.x, sim0); sim1 = fmaf(w6_2, k4.y, sim1);
              sim2 = fmaf(w6_3, k4.z, sim2); sim3 = fmaf(w6_4, k4.w, sim3); }
            { const float4 k4 = kt[r*3+2];
              sim0 = fmaf(w6_2, k4.x, sim0); sim1 = fmaf(w6_3, k4.y, sim1);
              sim2 = fmaf(w6_4, k4.z, sim2); sim3 = fmaf(w6_5, k4.w, sim3); }
        }

        float4 o;
        o.x = rowv[1].x * __builtin_amdgcn_rcpf(1.f + __expf(-sim0));
        o.y = rowv[1].y * __builtin_amdgcn_rcpf(1.f + __expf(-sim1));
        o.z = rowv[1].z * __builtin_amdgcn_rcpf(1.f + __expf(-sim2));
        o.w = rowv[1].w * __builtin_amdgcn_rcpf(1.f + __expf(-sim3));
        *(float4*)(out + ((size_t)(b * C_ + c) * H_ + y) * W_ + x0) = o;
    }
}

extern "C" void kernel_launch(void* const* d_in, const int* in_sizes, int n_in,
                              void* d_out, int out_size, void* d_ws, size_t ws_size,
                              hipStream_t stream) {
    const float* lr  = (const float*)d_in[0];  // [8,3,256,256]
    const float* hin = (const float*)d_in[1];  // [8,64,256,256]
    const float* w1  = (const float*)d_in[2];  // [64,3,3,3]
    const float* b1  = (const float*)d_in[3];  // [64]
    const float* w2  = (const float*)d_in[4];  // [9,64,1,1]
    const float* b2  = (const float*)d_in[5];  // [9]
    float* out = (float*)d_out;                // [8,64,256,256]

    const size_t kern_bytes = (size_t)B_ * H_ * TAPS * W_ * sizeof(float);

    if (ws_size >= kern_bytes) {
        float* kws = (float*)d_ws;
        hipLaunchKernelGGL(hsa_kern, dim3(B_ * H_), dim3(256), 0, stream,
                           lr, w1, b1, w2, b2, kws);
        hipLaunchKernelGGL(hsa_gate, dim3(B_ * H_), dim3(256), 0, stream,
                           hin, kws, out);
    } else {
        hipLaunchKernelGGL(hsa_fused, dim3(B_ * H_), dim3(256), 0, stream,
                           lr, hin, w1, b1, w2, b2, out);
    }
}

// Round 9
// 105.148 us; speedup vs baseline: 1.2366x; 1.2366x over previous
//
#include <hip/hip_runtime.h>
#include <hip/hip_bf16.h>
#include <math.h>

// Problem constants (from reference setup_inputs)
constexpr int B_  = 8;
constexpr int CIN = 3;
constexpr int C_  = 64;
constexpr int H_  = 256;
constexpr int W_  = 256;
constexpr int TAPS = 9;   // K*K, K=3

typedef float f32x4 __attribute__((ext_vector_type(4)));

// ============================================================================
// Kernel 1 (compute-bound, ~VALU roofline): kern = conv1x1(relu(conv3x3(lr)))
// ============================================================================
__global__ __launch_bounds__(256, 4)
void hsa_kern(const float* __restrict__ lr,
              const float* __restrict__ w1,
              const float* __restrict__ b1,
              const float* __restrict__ w2,
              const float* __restrict__ b2,
              float* __restrict__ kws)
{
    __shared__ float w2t[C_][12];       // transposed 1x1 weights

    const int tid = threadIdx.x;
    const int blk = blockIdx.x;         // 0 .. B_*H_-1
    const int b = blk / H_;
    const int y = blk % H_;

    for (int i = tid; i < TAPS * C_; i += 256) {
        const int t = i / C_;
        const int c = i % C_;
        w2t[c][t] = w2[i];
    }
    __syncthreads();

    const int x = tid;                  // 0..255
    float win[CIN][3][3];
    #pragma unroll
    for (int ci = 0; ci < CIN; ++ci) {
        #pragma unroll
        for (int r = 0; r < 3; ++r) {
            const int yy = y + r - 1;
            const bool vy = (unsigned)yy < (unsigned)H_;
            const float* row = lr + ((size_t)(b * CIN + ci) * H_ + yy) * W_;
            win[ci][r][0] = (vy && x > 0)       ? row[x - 1] : 0.f;
            win[ci][r][1] = vy                   ? row[x]     : 0.f;
            win[ci][r][2] = (vy && x < W_ - 1)  ? row[x + 1] : 0.f;
        }
    }

    float acc[TAPS];
    #pragma unroll
    for (int t = 0; t < TAPS; ++t) acc[t] = b2[t];

    for (int c = 0; c < C_; ++c) {
        const float* wc = w1 + c * 27;
        float h0 = b1[c], h1 = 0.f, h2 = 0.f;
        #pragma unroll
        for (int r = 0; r < 3; ++r)
            #pragma unroll
            for (int j = 0; j < 3; ++j) {
                h0 = fmaf(wc[(0 * 3 + r) * 3 + j], win[0][r][j], h0);
                h1 = fmaf(wc[(1 * 3 + r) * 3 + j], win[1][r][j], h1);
                h2 = fmaf(wc[(2 * 3 + r) * 3 + j], win[2][r][j], h2);
            }
        const float hsum = fmaxf((h0 + h1) + h2, 0.f);   // ReLU

        const float4 wa = *(const float4*)&w2t[c][0];
        const float4 wb = *(const float4*)&w2t[c][4];
        const float  w8 = w2t[c][8];
        acc[0] = fmaf(wa.x, hsum, acc[0]);
        acc[1] = fmaf(wa.y, hsum, acc[1]);
        acc[2] = fmaf(wa.z, hsum, acc[2]);
        acc[3] = fmaf(wa.w, hsum, acc[3]);
        acc[4] = fmaf(wb.x, hsum, acc[4]);
        acc[5] = fmaf(wb.y, hsum, acc[5]);
        acc[6] = fmaf(wb.z, hsum, acc[6]);
        acc[7] = fmaf(wb.w, hsum, acc[7]);
        acc[8] = fmaf(w8,  hsum, acc[8]);
    }

    float* kr = kws + (size_t)(b * H_ + y) * TAPS * W_;
    #pragma unroll
    for (int t = 0; t < TAPS; ++t) kr[t * W_ + x] = acc[t];
}

// ============================================================================
// Kernel 2 (gate): out = h * sigmoid(sum_taps shifted(h) * kern)
// y-SLIDING WINDOW, no LDS, no barriers.
// Block = (b, 8-row strip, 16-ch group); wave owns 4 channels; rows unrolled.
// Per iter, ISSUE ORDER = USE ORDER: kt (9 loads, used now) BEFORE next-row h
// (4 loads, used next iter). vmcnt is an in-order FIFO, so the compiler's
// wait before kt's first use leaves the h loads in flight through the whole
// compute phase -> structural 1-deep pipeline with zero asm.
// h loads per output row: ~1.1 float4/ch (vs 3 in R4-R8). All boundary
// handling folded into kt (row masks + lane-edge masks; R8-verified).
// ============================================================================
__global__ __launch_bounds__(256, 3)
void hsa_gate(const float* __restrict__ hin,
              const float* __restrict__ kws,
              float* __restrict__ out)
{
    const int tid = threadIdx.x;
    const int bid = blockIdx.x;          // 0..1023
    // bijective XCD swizzle: 1024 = 8 XCDs x 128; each XCD owns one batch.
    const int nb  = (bid & 7) * 128 + (bid >> 3);
    const int b     = nb >> 7;           // 0..7
    const int strip = (nb >> 2) & 31;    // 0..31
    const int cg    = nb & 3;            // 0..3  (consecutive nb share kern row)
    const int Y     = strip * 8;

    const int lane = tid & 63;
    const int wv   = tid >> 6;           // 0..3
    const int x0   = lane * 4;
    const int c0   = cg * 16 + wv * 4;   // this wave's 4 channels

    const size_t plane = (size_t)H_ * W_;
    const float* hb = hin + ((size_t)b * C_ + c0) * plane;
    float*       ob = out + ((size_t)b * C_ + c0) * plane;
    const float* kb = kws + (size_t)b * H_ * (TAPS * W_);

    const float lmask = (lane > 0)  ? 1.f : 0.f;
    const float rmask = (lane < 63) ? 1.f : 0.f;

    // ---- prologue: fill 3-row window for 4 channels ----
    f32x4 win[3][4];
    {
        const int ym = (Y > 0) ? (Y - 1) : 0;   // clamped; masked via kt
        #pragma unroll
        for (int i = 0; i < 4; ++i) {
            win[0][i] = *(const f32x4*)(hb + i * plane + (size_t)ym      * W_ + x0);
            win[1][i] = *(const f32x4*)(hb + i * plane + (size_t)Y       * W_ + x0);
            win[2][i] = *(const f32x4*)(hb + i * plane + (size_t)(Y + 1) * W_ + x0);
        }
    }

    #pragma unroll
    for (int yy = 0; yy < 8; ++yy) {
        const int yg = Y + yy;

        // 1. kt loads FIRST (needed this iter; L1/L2-hot across waves/blocks)
        const float* kr = kb + (size_t)yg * (TAPS * W_) + x0;
        f32x4 kt[TAPS];
        #pragma unroll
        for (int t = 0; t < TAPS; ++t) kt[t] = *(const f32x4*)(kr + t * W_);

        // 2. next h row AFTER kt (needed next iter; stays in flight)
        f32x4 nxt[4];
        if (yy < 7) {
            const int yn = (yg + 2 < H_) ? (yg + 2) : (H_ - 1);
            #pragma unroll
            for (int i = 0; i < 4; ++i)
                nxt[i] = *(const f32x4*)(hb + i * plane + (size_t)yn * W_ + x0);
        }

        // 3. fold ALL boundary masks into kt
        const float m0 = (yg > 0)      ? 1.f : 0.f;
        const float m2 = (yg < H_ - 1) ? 1.f : 0.f;
        #pragma unroll
        for (int t = 0; t < 3; ++t) { kt[t] *= m0; kt[6 + t] *= m2; }
        kt[0].x *= lmask; kt[3].x *= lmask; kt[6].x *= lmask;
        kt[2].w *= rmask; kt[5].w *= rmask; kt[8].w *= rmask;

        // 4. compute 4 channels (pure FMA + 2 shuffles per row)
        float sim[4][4];
        #pragma unroll
        for (int i = 0; i < 4; ++i)
            #pragma unroll
            for (int j = 0; j < 4; ++j) sim[i][j] = 0.f;

        #pragma unroll
        for (int r = 0; r < 3; ++r) {
            const int sl = (yy + r) % 3;          // compile-time after unroll
            const f32x4 k0 = kt[r * 3 + 0];
            const f32x4 k1 = kt[r * 3 + 1];
            const f32x4 k2 = kt[r * 3 + 2];
            #pragma unroll
            for (int i = 0; i < 4; ++i) {
                const f32x4 cv = win[sl][i];
                const float l  = __shfl_up(cv.w, 1);    // x0-1 (lane0 masked via kt)
                const float rr = __shfl_down(cv.x, 1);  // x0+4 (lane63 masked via kt)
                sim[i][0] = fmaf(l,    k0.x, fmaf(cv.x, k1.x, fmaf(cv.y, k2.x, sim[i][0])));
                sim[i][1] = fmaf(cv.x, k0.y, fmaf(cv.y, k1.y, fmaf(cv.z, k2.y, sim[i][1])));
                sim[i][2] = fmaf(cv.y, k0.z, fmaf(cv.z, k1.z, fmaf(cv.w, k2.z, sim[i][2])));
                sim[i][3] = fmaf(cv.z, k0.w, fmaf(cv.w, k1.w, fmaf(rr,   k2.w, sim[i][3])));
            }
        }

        // 5. gate + store
        #pragma unroll
        for (int i = 0; i < 4; ++i) {
            const f32x4 ctr = win[(yy + 1) % 3][i];
            f32x4 o;
            o.x = ctr.x * __builtin_amdgcn_rcpf(1.f + __expf(-sim[i][0]));
            o.y = ctr.y * __builtin_amdgcn_rcpf(1.f + __expf(-sim[i][1]));
            o.z = ctr.z * __builtin_amdgcn_rcpf(1.f + __expf(-sim[i][2]));
            o.w = ctr.w * __builtin_amdgcn_rcpf(1.f + __expf(-sim[i][3]));
            *(f32x4*)(ob + i * plane + (size_t)yg * W_ + x0) = o;
        }

        // 6. rotate window (pure SSA renaming after full unroll)
        if (yy < 7) {
            #pragma unroll
            for (int i = 0; i < 4; ++i) win[yy % 3][i] = nxt[i];
        }
    }
}

// ============================================================================
// Fallback: single fused kernel (used only if ws_size is too small)
// ============================================================================
__global__ __launch_bounds__(256, 4)
void hsa_fused(const float* __restrict__ lr,
               const float* __restrict__ hin,
               const float* __restrict__ w1,
               const float* __restrict__ b1,
               const float* __restrict__ w2,
               const float* __restrict__ b2,
               float* __restrict__ out)
{
    __shared__ float kernS[TAPS][W_];
    __shared__ float w2t[C_][12];

    const int tid = threadIdx.x;
    const int blk = blockIdx.x;
    const int b = blk / H_;
    const int y = blk % H_;

    for (int i = tid; i < TAPS * C_; i += 256) {
        const int t = i / C_;
        const int c = i % C_;
        w2t[c][t] = w2[i];
    }
    __syncthreads();

    {
        const int x = tid;
        float win[CIN][3][3];
        #pragma unroll
        for (int ci = 0; ci < CIN; ++ci)
            #pragma unroll
            for (int r = 0; r < 3; ++r) {
                const int yy = y + r - 1;
                const bool vy = (unsigned)yy < (unsigned)H_;
                const float* row = lr + ((size_t)(b * CIN + ci) * H_ + yy) * W_;
                win[ci][r][0] = (vy && x > 0)      ? row[x - 1] : 0.f;
                win[ci][r][1] = vy                  ? row[x]     : 0.f;
                win[ci][r][2] = (vy && x < W_ - 1) ? row[x + 1] : 0.f;
            }

        float acc[TAPS];
        #pragma unroll
        for (int t = 0; t < TAPS; ++t) acc[t] = b2[t];

        for (int c = 0; c < C_; ++c) {
            const float* wc = w1 + c * 27;
            float h0 = b1[c], h1 = 0.f, h2 = 0.f;
            #pragma unroll
            for (int r = 0; r < 3; ++r)
                #pragma unroll
                for (int j = 0; j < 3; ++j) {
                    h0 = fmaf(wc[(0 * 3 + r) * 3 + j], win[0][r][j], h0);
                    h1 = fmaf(wc[(1 * 3 + r) * 3 + j], win[1][r][j], h1);
                    h2 = fmaf(wc[(2 * 3 + r) * 3 + j], win[2][r][j], h2);
                }
            const float hsum = fmaxf((h0 + h1) + h2, 0.f);
            const float4 wa = *(const float4*)&w2t[c][0];
            const float4 wb = *(const float4*)&w2t[c][4];
            const float  w8 = w2t[c][8];
            acc[0] = fmaf(wa.x, hsum, acc[0]);
            acc[1] = fmaf(wa.y, hsum, acc[1]);
            acc[2] = fmaf(wa.z, hsum, acc[2]);
            acc[3] = fmaf(wa.w, hsum, acc[3]);
            acc[4] = fmaf(wb.x, hsum, acc[4]);
            acc[5] = fmaf(wb.y, hsum, acc[5]);
            acc[6] = fmaf(wb.z, hsum, acc[6]);
            acc[7] = fmaf(wb.w, hsum, acc[7]);
            acc[8] = fmaf(w8,  hsum, acc[8]);
        }
        #pragma unroll
        for (int t = 0; t < TAPS; ++t) kernS[t][x] = acc[t];
    }
    __syncthreads();

    const int lane = tid & 63;
    const int wav  = tid >> 6;
    const int x0   = lane * 4;

    float4 kt[TAPS];
    #pragma unroll
    for (int t = 0; t < TAPS; ++t) kt[t] = *(const float4*)&kernS[t][x0];

    #pragma unroll 4
    for (int cc = 0; cc < 16; ++cc) {
        const int c = wav * 16 + cc;
        const float* hb = hin + (size_t)(b * C_ + c) * H_ * W_;

        float4 rowv[3];
        float  lft[3], rgt[3];
        #pragma unroll
        for (int r = 0; r < 3; ++r) {
            const int yy = y + r - 1;
            const bool vy = (unsigned)yy < (unsigned)H_;
            float4 m;
            if (vy) m = *(const float4*)(hb + (size_t)yy * W_ + x0);
            else    m = make_float4(0.f, 0.f, 0.f, 0.f);
            rowv[r] = m;
            float l  = __shfl_up(m.w, 1);
            float rr = __shfl_down(m.x, 1);
            if (lane == 0)  l  = 0.f;
            if (lane == 63) rr = 0.f;
            lft[r] = l; rgt[r] = rr;
        }

        float sim0 = 0.f, sim1 = 0.f, sim2 = 0.f, sim3 = 0.f;
        #pragma unroll
        for (int r = 0; r < 3; ++r) {
            const float w6_0 = lft[r];
            const float w6_1 = rowv[r].x;
            const float w6_2 = rowv[r].y;
            const float w6_3 = rowv[r].z;
            const float w6_4 = rowv[r].w;
            const float w6_5 = rgt[r];
            { const float4 k4 = kt[r*3+0];
              sim0 = fmaf(w6_0, k4.x, sim0); sim1 = fmaf(w6_1, k4.y, sim1);
              sim2 = fmaf(w6_2, k4.z, sim2); sim3 = fmaf(w6_3, k4.w, sim3); }
            { const float4 k4 = kt[r*3+1];
              sim0 = fmaf(w6_1, k4.x, sim0); sim1 = fmaf(w6_2, k4.y, sim1);
              sim2 = fmaf(w6_3, k4.z, sim2); sim3 = fmaf(w6_4, k4.w, sim3); }
            { const float4 k4 = kt[r*3+2];
              sim0 = fmaf(w6_2, k4.x, sim0); sim1 = fmaf(w6_3, k4.y, sim1);
              sim2 = fmaf(w6_4, k4.z, sim2); sim3 = fmaf(w6_5, k4.w, sim3); }
        }

        float4 o;
        o.x = rowv[1].x * __builtin_amdgcn_rcpf(1.f + __expf(-sim0));
        o.y = rowv[1].y * __builtin_amdgcn_rcpf(1.f + __expf(-sim1));
        o.z = rowv[1].z * __builtin_amdgcn_rcpf(1.f + __expf(-sim2));
        o.w = rowv[1].w * __builtin_amdgcn_rcpf(1.f + __expf(-sim3));
        *(float4*)(out + ((size_t)(b * C_ + c) * H_ + y) * W_ + x0) = o;
    }
}

extern "C" void kernel_launch(void* const* d_in, const int* in_sizes, int n_in,
                              void* d_out, int out_size, void* d_ws, size_t ws_size,
                              hipStream_t stream) {
    const float* lr  = (const float*)d_in[0];  // [8,3,256,256]
    const float* hin = (const float*)d_in[1];  // [8,64,256,256]
    const float* w1  = (const float*)d_in[2];  // [64,3,3,3]
    const float* b1  = (const float*)d_in[3];  // [64]
    const float* w2  = (const float*)d_in[4];  // [9,64,1,1]
    const float* b2  = (const float*)d_in[5];  // [9]
    float* out = (float*)d_out;                // [8,64,256,256]

    const size_t kern_bytes = (size_t)B_ * H_ * TAPS * W_ * sizeof(float);

    if (ws_size >= kern_bytes) {
        float* kws = (float*)d_ws;
        hipLaunchKernelGGL(hsa_kern, dim3(B_ * H_), dim3(256), 0, stream,
                           lr, w1, b1, w2, b2, kws);
        // 8 batches x 32 strips x 4 channel-groups = 1024 blocks
        hipLaunchKernelGGL(hsa_gate, dim3(1024), dim3(256), 0, stream,
                           hin, kws, out);
    } else {
        hipLaunchKernelGGL(hsa_fused, dim3(B_ * H_), dim3(256), 0, stream,
                           lr, hin, w1, b1, w2, b2, out);
    }
}

// Round 10
// 104.659 us; speedup vs baseline: 1.2424x; 1.0047x over previous
//
#include <hip/hip_runtime.h>
#include <hip/hip_bf16.h>
#include <math.h>

// Problem constants (from reference setup_inputs)
constexpr int B_  = 8;
constexpr int CIN = 3;
constexpr int C_  = 64;
constexpr int H_  = 256;
constexpr int W_  = 256;
constexpr int TAPS = 9;   // K*K, K=3

typedef float f32x4 __attribute__((ext_vector_type(4)));

// ============================================================================
// Kernel 1 (compute-bound, ~VALU roofline): kern = conv1x1(relu(conv3x3(lr)))
// ============================================================================
__global__ __launch_bounds__(256, 4)
void hsa_kern(const float* __restrict__ lr,
              const float* __restrict__ w1,
              const float* __restrict__ b1,
              const float* __restrict__ w2,
              const float* __restrict__ b2,
              float* __restrict__ kws)
{
    __shared__ float w2t[C_][12];       // transposed 1x1 weights

    const int tid = threadIdx.x;
    const int blk = blockIdx.x;         // 0 .. B_*H_-1
    const int b = blk / H_;
    const int y = blk % H_;

    for (int i = tid; i < TAPS * C_; i += 256) {
        const int t = i / C_;
        const int c = i % C_;
        w2t[c][t] = w2[i];
    }
    __syncthreads();

    const int x = tid;                  // 0..255
    float win[CIN][3][3];
    #pragma unroll
    for (int ci = 0; ci < CIN; ++ci) {
        #pragma unroll
        for (int r = 0; r < 3; ++r) {
            const int yy = y + r - 1;
            const bool vy = (unsigned)yy < (unsigned)H_;
            const float* row = lr + ((size_t)(b * CIN + ci) * H_ + yy) * W_;
            win[ci][r][0] = (vy && x > 0)       ? row[x - 1] : 0.f;
            win[ci][r][1] = vy                   ? row[x]     : 0.f;
            win[ci][r][2] = (vy && x < W_ - 1)  ? row[x + 1] : 0.f;
        }
    }

    float acc[TAPS];
    #pragma unroll
    for (int t = 0; t < TAPS; ++t) acc[t] = b2[t];

    for (int c = 0; c < C_; ++c) {
        const float* wc = w1 + c * 27;
        float h0 = b1[c], h1 = 0.f, h2 = 0.f;
        #pragma unroll
        for (int r = 0; r < 3; ++r)
            #pragma unroll
            for (int j = 0; j < 3; ++j) {
                h0 = fmaf(wc[(0 * 3 + r) * 3 + j], win[0][r][j], h0);
                h1 = fmaf(wc[(1 * 3 + r) * 3 + j], win[1][r][j], h1);
                h2 = fmaf(wc[(2 * 3 + r) * 3 + j], win[2][r][j], h2);
            }
        const float hsum = fmaxf((h0 + h1) + h2, 0.f);   // ReLU

        const float4 wa = *(const float4*)&w2t[c][0];
        const float4 wb = *(const float4*)&w2t[c][4];
        const float  w8 = w2t[c][8];
        acc[0] = fmaf(wa.x, hsum, acc[0]);
        acc[1] = fmaf(wa.y, hsum, acc[1]);
        acc[2] = fmaf(wa.z, hsum, acc[2]);
        acc[3] = fmaf(wa.w, hsum, acc[3]);
        acc[4] = fmaf(wb.x, hsum, acc[4]);
        acc[5] = fmaf(wb.y, hsum, acc[5]);
        acc[6] = fmaf(wb.z, hsum, acc[6]);
        acc[7] = fmaf(wb.w, hsum, acc[7]);
        acc[8] = fmaf(w8,  hsum, acc[8]);
    }

    float* kr = kws + (size_t)(b * H_ + y) * TAPS * W_;
    #pragma unroll
    for (int t = 0; t < TAPS; ++t) kr[t * W_ + x] = acc[t];
}

// ============================================================================
// Kernel 2 (gate): out = h * sigmoid(sum_taps shifted(h) * kern)
// y-sliding window + REGISTER DOUBLE-BUFFERED kt:
//   iter yy computes with ktbuf[yy&1] (loaded LAST iter) while issuing
//   kern[yg+1] into ktbuf[(yy+1)&1] and h[yg+2] into nxt. So neither the kt
//   L2 latency (R9's exposed ~400cy/iter) nor most of the h HBM latency sits
//   on the critical path. All indices compile-time after full unroll.
// Boundary handling folded into the live kt buffer in-place (it dies this
// iter; parity rotation frees it for the yy+2 prefetch).
// ============================================================================
__global__ __launch_bounds__(256, 2)
void hsa_gate(const float* __restrict__ hin,
              const float* __restrict__ kws,
              float* __restrict__ out)
{
    const int tid = threadIdx.x;
    const int bid = blockIdx.x;          // 0..1023
    // bijective XCD swizzle: 1024 = 8 XCDs x 128; each XCD owns one batch.
    const int nb  = (bid & 7) * 128 + (bid >> 3);
    const int b     = nb >> 7;           // 0..7
    const int strip = (nb >> 2) & 31;    // 0..31
    const int cg    = nb & 3;            // 0..3
    const int Y     = strip * 8;

    const int lane = tid & 63;
    const int wv   = tid >> 6;           // 0..3
    const int x0   = lane * 4;
    const int c0   = cg * 16 + wv * 4;   // this wave's 4 channels

    const size_t plane = (size_t)H_ * W_;
    const float* hb = hin + ((size_t)b * C_ + c0) * plane;
    float*       ob = out + ((size_t)b * C_ + c0) * plane;
    const float* kb = kws + (size_t)b * H_ * (TAPS * W_) + x0;

    const float lmask = (lane > 0)  ? 1.f : 0.f;
    const float rmask = (lane < 63) ? 1.f : 0.f;

    f32x4 win[3][4];        // 3-row window x 4 channels
    f32x4 ktbuf[2][TAPS];   // double-buffered kern taps

    // ---- prologue ----
    {
        const int ym = (Y > 0) ? (Y - 1) : 0;   // clamped; masked via kt
        #pragma unroll
        for (int i = 0; i < 4; ++i)
            win[0][i] = *(const f32x4*)(hb + i * plane + (size_t)ym      * W_ + x0);
        #pragma unroll
        for (int i = 0; i < 4; ++i)
            win[1][i] = *(const f32x4*)(hb + i * plane + (size_t)Y       * W_ + x0);
        #pragma unroll
        for (int i = 0; i < 4; ++i)
            win[2][i] = *(const f32x4*)(hb + i * plane + (size_t)(Y + 1) * W_ + x0);
        const float* kr = kb + (size_t)Y * (TAPS * W_);
        #pragma unroll
        for (int t = 0; t < TAPS; ++t)
            ktbuf[0][t] = *(const f32x4*)(kr + t * W_);
    }

    #pragma unroll
    for (int yy = 0; yy < 8; ++yy) {
        const int yg = Y + yy;
        const int cur = yy & 1;

        // 1. issue NEXT kern row into the alternate buffer (used next iter)
        if (yy < 7) {
            const float* kr = kb + (size_t)(yg + 1) * (TAPS * W_);
            #pragma unroll
            for (int t = 0; t < TAPS; ++t)
                ktbuf[cur ^ 1][t] = *(const f32x4*)(kr + t * W_);
        }

        // 2. issue next h row (enters window at end of this iter)
        f32x4 nxt[4];
        if (yy < 7) {
            const int yn = (yg + 2 < H_) ? (yg + 2) : (H_ - 1);
            #pragma unroll
            for (int i = 0; i < 4; ++i)
                nxt[i] = *(const f32x4*)(hb + i * plane + (size_t)yn * W_ + x0);
        }

        // 3. fold boundary masks into the CURRENT kt buffer in-place
        const float m0 = (yg > 0)      ? 1.f : 0.f;
        const float m2 = (yg < H_ - 1) ? 1.f : 0.f;
        #pragma unroll
        for (int t = 0; t < 3; ++t) { ktbuf[cur][t] *= m0; ktbuf[cur][6 + t] *= m2; }
        ktbuf[cur][0].x *= lmask; ktbuf[cur][3].x *= lmask; ktbuf[cur][6].x *= lmask;
        ktbuf[cur][2].w *= rmask; ktbuf[cur][5].w *= rmask; ktbuf[cur][8].w *= rmask;

        // 4. compute 4 channels with the CURRENT (already-resident) kt
        float sim[4][4];
        #pragma unroll
        for (int i = 0; i < 4; ++i)
            #pragma unroll
            for (int j = 0; j < 4; ++j) sim[i][j] = 0.f;

        #pragma unroll
        for (int r = 0; r < 3; ++r) {
            const int sl = (yy + r) % 3;          // compile-time after unroll
            const f32x4 k0 = ktbuf[cur][r * 3 + 0];
            const f32x4 k1 = ktbuf[cur][r * 3 + 1];
            const f32x4 k2 = ktbuf[cur][r * 3 + 2];
            #pragma unroll
            for (int i = 0; i < 4; ++i) {
                const f32x4 cv = win[sl][i];
                const float l  = __shfl_up(cv.w, 1);    // x0-1 (lane0 masked via kt)
                const float rr = __shfl_down(cv.x, 1);  // x0+4 (lane63 masked via kt)
                sim[i][0] = fmaf(l,    k0.x, fmaf(cv.x, k1.x, fmaf(cv.y, k2.x, sim[i][0])));
                sim[i][1] = fmaf(cv.x, k0.y, fmaf(cv.y, k1.y, fmaf(cv.z, k2.y, sim[i][1])));
                sim[i][2] = fmaf(cv.y, k0.z, fmaf(cv.z, k1.z, fmaf(cv.w, k2.z, sim[i][2])));
                sim[i][3] = fmaf(cv.z, k0.w, fmaf(cv.w, k1.w, fmaf(rr,   k2.w, sim[i][3])));
            }
        }

        // 5. gate + store
        #pragma unroll
        for (int i = 0; i < 4; ++i) {
            const f32x4 ctr = win[(yy + 1) % 3][i];
            f32x4 o;
            o.x = ctr.x * __builtin_amdgcn_rcpf(1.f + __expf(-sim[i][0]));
            o.y = ctr.y * __builtin_amdgcn_rcpf(1.f + __expf(-sim[i][1]));
            o.z = ctr.z * __builtin_amdgcn_rcpf(1.f + __expf(-sim[i][2]));
            o.w = ctr.w * __builtin_amdgcn_rcpf(1.f + __expf(-sim[i][3]));
            *(f32x4*)(ob + i * plane + (size_t)yg * W_ + x0) = o;
        }

        // 6. rotate window (SSA renaming after full unroll)
        if (yy < 7) {
            #pragma unroll
            for (int i = 0; i < 4; ++i) win[yy % 3][i] = nxt[i];
        }
    }
}

// ============================================================================
// Fallback: single fused kernel (used only if ws_size is too small)
// ============================================================================
__global__ __launch_bounds__(256, 4)
void hsa_fused(const float* __restrict__ lr,
               const float* __restrict__ hin,
               const float* __restrict__ w1,
               const float* __restrict__ b1,
               const float* __restrict__ w2,
               const float* __restrict__ b2,
               float* __restrict__ out)
{
    __shared__ float kernS[TAPS][W_];
    __shared__ float w2t[C_][12];

    const int tid = threadIdx.x;
    const int blk = blockIdx.x;
    const int b = blk / H_;
    const int y = blk % H_;

    for (int i = tid; i < TAPS * C_; i += 256) {
        const int t = i / C_;
        const int c = i % C_;
        w2t[c][t] = w2[i];
    }
    __syncthreads();

    {
        const int x = tid;
        float win[CIN][3][3];
        #pragma unroll
        for (int ci = 0; ci < CIN; ++ci)
            #pragma unroll
            for (int r = 0; r < 3; ++r) {
                const int yy = y + r - 1;
                const bool vy = (unsigned)yy < (unsigned)H_;
                const float* row = lr + ((size_t)(b * CIN + ci) * H_ + yy) * W_;
                win[ci][r][0] = (vy && x > 0)      ? row[x - 1] : 0.f;
                win[ci][r][1] = vy                  ? row[x]     : 0.f;
                win[ci][r][2] = (vy && x < W_ - 1) ? row[x + 1] : 0.f;
            }

        float acc[TAPS];
        #pragma unroll
        for (int t = 0; t < TAPS; ++t) acc[t] = b2[t];

        for (int c = 0; c < C_; ++c) {
            const float* wc = w1 + c * 27;
            float h0 = b1[c], h1 = 0.f, h2 = 0.f;
            #pragma unroll
            for (int r = 0; r < 3; ++r)
                #pragma unroll
                for (int j = 0; j < 3; ++j) {
                    h0 = fmaf(wc[(0 * 3 + r) * 3 + j], win[0][r][j], h0);
                    h1 = fmaf(wc[(1 * 3 + r) * 3 + j], win[1][r][j], h1);
                    h2 = fmaf(wc[(2 * 3 + r) * 3 + j], win[2][r][j], h2);
                }
            const float hsum = fmaxf((h0 + h1) + h2, 0.f);
            const float4 wa = *(const float4*)&w2t[c][0];
            const float4 wb = *(const float4*)&w2t[c][4];
            const float  w8 = w2t[c][8];
            acc[0] = fmaf(wa.x, hsum, acc[0]);
            acc[1] = fmaf(wa.y, hsum, acc[1]);
            acc[2] = fmaf(wa.z, hsum, acc[2]);
            acc[3] = fmaf(wa.w, hsum, acc[3]);
            acc[4] = fmaf(wb.x, hsum, acc[4]);
            acc[5] = fmaf(wb.y, hsum, acc[5]);
            acc[6] = fmaf(wb.z, hsum, acc[6]);
            acc[7] = fmaf(wb.w, hsum, acc[7]);
            acc[8] = fmaf(w8,  hsum, acc[8]);
        }
        #pragma unroll
        for (int t = 0; t < TAPS; ++t) kernS[t][x] = acc[t];
    }
    __syncthreads();

    const int lane = tid & 63;
    const int wav  = tid >> 6;
    const int x0   = lane * 4;

    float4 kt[TAPS];
    #pragma unroll
    for (int t = 0; t < TAPS; ++t) kt[t] = *(const float4*)&kernS[t][x0];

    #pragma unroll 4
    for (int cc = 0; cc < 16; ++cc) {
        const int c = wav * 16 + cc;
        const float* hb = hin + (size_t)(b * C_ + c) * H_ * W_;

        float4 rowv[3];
        float  lft[3], rgt[3];
        #pragma unroll
        for (int r = 0; r < 3; ++r) {
            const int yy = y + r - 1;
            const bool vy = (unsigned)yy < (unsigned)H_;
            float4 m;
            if (vy) m = *(const float4*)(hb + (size_t)yy * W_ + x0);
            else    m = make_float4(0.f, 0.f, 0.f, 0.f);
            rowv[r] = m;
            float l  = __shfl_up(m.w, 1);
            float rr = __shfl_down(m.x, 1);
            if (lane == 0)  l  = 0.f;
            if (lane == 63) rr = 0.f;
            lft[r] = l; rgt[r] = rr;
        }

        float sim0 = 0.f, sim1 = 0.f, sim2 = 0.f, sim3 = 0.f;
        #pragma unroll
        for (int r = 0; r < 3; ++r) {
            const float w6_0 = lft[r];
            const float w6_1 = rowv[r].x;
            const float w6_2 = rowv[r].y;
            const float w6_3 = rowv[r].z;
            const float w6_4 = rowv[r].w;
            const float w6_5 = rgt[r];
            { const float4 k4 = kt[r*3+0];
              sim0 = fmaf(w6_0, k4.x, sim0); sim1 = fmaf(w6_1, k4.y, sim1);
              sim2 = fmaf(w6_2, k4.z, sim2); sim3 = fmaf(w6_3, k4.w, sim3); }
            { const float4 k4 = kt[r*3+1];
              sim0 = fmaf(w6_1, k4.x, sim0); sim1 = fmaf(w6_2, k4.y, sim1);
              sim2 = fmaf(w6_3, k4.z, sim2); sim3 = fmaf(w6_4, k4.w, sim3); }
            { const float4 k4 = kt[r*3+2];
              sim0 = fmaf(w6_2, k4.x, sim0); sim1 = fmaf(w6_3, k4.y, sim1);
              sim2 = fmaf(w6_4, k4.z, sim2); sim3 = fmaf(w6_5, k4.w, sim3); }
        }

        float4 o;
        o.x = rowv[1].x * __builtin_amdgcn_rcpf(1.f + __expf(-sim0));
        o.y = rowv[1].y * __builtin_amdgcn_rcpf(1.f + __expf(-sim1));
        o.z = rowv[1].z * __builtin_amdgcn_rcpf(1.f + __expf(-sim2));
        o.w = rowv[1].w * __builtin_amdgcn_rcpf(1.f + __expf(-sim3));
        *(float4*)(out + ((size_t)(b * C_ + c) * H_ + y) * W_ + x0) = o;
    }
}

extern "C" void kernel_launch(void* const* d_in, const int* in_sizes, int n_in,
                              void* d_out, int out_size, void* d_ws, size_t ws_size,
                              hipStream_t stream) {
    const float* lr  = (const float*)d_in[0];  // [8,3,256,256]
    const float* hin = (const float*)d_in[1];  // [8,64,256,256]
    const float* w1  = (const float*)d_in[2];  // [64,3,3,3]
    const float* b1  = (const float*)d_in[3];  // [64]
    const float* w2  = (const float*)d_in[4];  // [9,64,1,1]
    const float* b2  = (const float*)d_in[5];  // [9]
    float* out = (float*)d_out;                // [8,64,256,256]

    const size_t kern_bytes = (size_t)B_ * H_ * TAPS * W_ * sizeof(float);

    if (ws_size >= kern_bytes) {
        float* kws = (float*)d_ws;
        hipLaunchKernelGGL(hsa_kern, dim3(B_ * H_), dim3(256), 0, stream,
                           lr, w1, b1, w2, b2, kws);
        // 8 batches x 32 strips x 4 channel-groups = 1024 blocks
        hipLaunchKernelGGL(hsa_gate, dim3(1024), dim3(256), 0, stream,
                           hin, kws, out);
    } else {
        hipLaunchKernelGGL(hsa_fused, dim3(B_ * H_), dim3(256), 0, stream,
                           lr, hin, w1, b1, w2, b2, out);
    }
}

// Round 11
// 94.871 us; speedup vs baseline: 1.3705x; 1.1032x over previous
//
#include <hip/hip_runtime.h>
#include <hip/hip_bf16.h>
#include <math.h>

// Problem constants (from reference setup_inputs)
constexpr int B_  = 8;
constexpr int CIN = 3;
constexpr int C_  = 64;
constexpr int H_  = 256;
constexpr int W_  = 256;
constexpr int TAPS = 9;   // K*K, K=3

typedef float f32x4 __attribute__((ext_vector_type(4)));

// ============================================================================
// Kernel 1 (compute-bound, ~VALU roofline): kern = conv1x1(relu(conv3x3(lr)))
// ============================================================================
__global__ __launch_bounds__(256, 4)
void hsa_kern(const float* __restrict__ lr,
              const float* __restrict__ w1,
              const float* __restrict__ b1,
              const float* __restrict__ w2,
              const float* __restrict__ b2,
              float* __restrict__ kws)
{
    __shared__ float w2t[C_][12];       // transposed 1x1 weights

    const int tid = threadIdx.x;
    const int blk = blockIdx.x;         // 0 .. B_*H_-1
    const int b = blk / H_;
    const int y = blk % H_;

    for (int i = tid; i < TAPS * C_; i += 256) {
        const int t = i / C_;
        const int c = i % C_;
        w2t[c][t] = w2[i];
    }
    __syncthreads();

    const int x = tid;                  // 0..255
    float win[CIN][3][3];
    #pragma unroll
    for (int ci = 0; ci < CIN; ++ci) {
        #pragma unroll
        for (int r = 0; r < 3; ++r) {
            const int yy = y + r - 1;
            const bool vy = (unsigned)yy < (unsigned)H_;
            const float* row = lr + ((size_t)(b * CIN + ci) * H_ + yy) * W_;
            win[ci][r][0] = (vy && x > 0)       ? row[x - 1] : 0.f;
            win[ci][r][1] = vy                   ? row[x]     : 0.f;
            win[ci][r][2] = (vy && x < W_ - 1)  ? row[x + 1] : 0.f;
        }
    }

    float acc[TAPS];
    #pragma unroll
    for (int t = 0; t < TAPS; ++t) acc[t] = b2[t];

    for (int c = 0; c < C_; ++c) {
        const float* wc = w1 + c * 27;
        float h0 = b1[c], h1 = 0.f, h2 = 0.f;
        #pragma unroll
        for (int r = 0; r < 3; ++r)
            #pragma unroll
            for (int j = 0; j < 3; ++j) {
                h0 = fmaf(wc[(0 * 3 + r) * 3 + j], win[0][r][j], h0);
                h1 = fmaf(wc[(1 * 3 + r) * 3 + j], win[1][r][j], h1);
                h2 = fmaf(wc[(2 * 3 + r) * 3 + j], win[2][r][j], h2);
            }
        const float hsum = fmaxf((h0 + h1) + h2, 0.f);   // ReLU

        const float4 wa = *(const float4*)&w2t[c][0];
        const float4 wb = *(const float4*)&w2t[c][4];
        const float  w8 = w2t[c][8];
        acc[0] = fmaf(wa.x, hsum, acc[0]);
        acc[1] = fmaf(wa.y, hsum, acc[1]);
        acc[2] = fmaf(wa.z, hsum, acc[2]);
        acc[3] = fmaf(wa.w, hsum, acc[3]);
        acc[4] = fmaf(wb.x, hsum, acc[4]);
        acc[5] = fmaf(wb.y, hsum, acc[5]);
        acc[6] = fmaf(wb.z, hsum, acc[6]);
        acc[7] = fmaf(wb.w, hsum, acc[7]);
        acc[8] = fmaf(w8,  hsum, acc[8]);
    }

    float* kr = kws + (size_t)(b * H_ + y) * TAPS * W_;
    #pragma unroll
    for (int t = 0; t < TAPS; ++t) kr[t * W_ + x] = acc[t];
}

// ============================================================================
// Kernel 2 (gate): out = h * sigmoid(sum_taps shifted(h) * kern)
// R10 sliding window + LDS-STAGED kern (the R11 change):
//   The 4 waves of a block read IDENTICAL kern rows (kern is channel-
//   independent) -> R10 read each row 16x at L2/L3 level (295 MB). Staging
//   each row once per block in double-buffered LDS cuts that 4x (-> 74 MB).
//   Rationale: BW is occupancy-insensitive across R4(84%)/R10(26%) at
//   ~2.7 TB/s -> the cache fabric (~6.5-7 TB/s combined) is the saturated
//   resource, so the lever is cache-level traffic, not latency hiding.
// Per iter: (a) next kern row -> regs, (b) compute with ksh[cur] + window,
// (c) ds_write regs -> ksh[cur^1], one barrier. Staging latency hides under
// compute; LDS read latency (~120cy) is negligible vs L2 (~400cy).
// ============================================================================
__global__ __launch_bounds__(256, 3)
void hsa_gate(const float* __restrict__ hin,
              const float* __restrict__ kws,
              float* __restrict__ out)
{
    __shared__ float ksh[2][TAPS][W_];   // 18 KB double-buffered kern rows

    const int tid = threadIdx.x;
    const int bid = blockIdx.x;          // 0..1023
    // bijective XCD swizzle: 1024 = 8 XCDs x 128; each XCD owns one batch.
    const int nb  = (bid & 7) * 128 + (bid >> 3);
    const int b     = nb >> 7;           // 0..7
    const int strip = (nb >> 2) & 31;    // 0..31
    const int cg    = nb & 3;            // 0..3
    const int Y     = strip * 8;

    const int lane = tid & 63;
    const int wv   = tid >> 6;           // 0..3
    const int x0   = lane * 4;
    const int c0   = cg * 16 + wv * 4;   // this wave's 4 channels

    const size_t plane = (size_t)H_ * W_;
    const float* hb = hin + ((size_t)b * C_ + c0) * plane;
    float*       ob = out + ((size_t)b * C_ + c0) * plane;
    const float* kbase = kws + (size_t)b * H_ * (TAPS * W_);

    const float lmask = (lane > 0)  ? 1.f : 0.f;
    const float rmask = (lane < 63) ? 1.f : 0.f;

    f32x4 win[3][4];        // 3-row h window x 4 channels

    // ---- prologue: h window + stage kern row Y into ksh[0] ----
    {
        const int ym = (Y > 0) ? (Y - 1) : 0;   // clamped; masked via kt
        #pragma unroll
        for (int i = 0; i < 4; ++i)
            win[0][i] = *(const f32x4*)(hb + i * plane + (size_t)ym      * W_ + x0);
        #pragma unroll
        for (int i = 0; i < 4; ++i)
            win[1][i] = *(const f32x4*)(hb + i * plane + (size_t)Y       * W_ + x0);
        #pragma unroll
        for (int i = 0; i < 4; ++i)
            win[2][i] = *(const f32x4*)(hb + i * plane + (size_t)(Y + 1) * W_ + x0);

        const float* kr = kbase + (size_t)Y * (TAPS * W_);
        #pragma unroll
        for (int t = 0; t < TAPS; ++t)
            ksh[0][t][tid] = kr[t * W_ + tid];   // 9 coalesced 1KB loads/block
    }
    __syncthreads();

    #pragma unroll
    for (int yy = 0; yy < 8; ++yy) {
        const int yg  = Y + yy;
        const int cur = yy & 1;

        // (a) next kern row -> registers (issued early, consumed after compute)
        float kst[TAPS];
        if (yy < 7) {
            const float* kr = kbase + (size_t)(yg + 1) * (TAPS * W_);
            #pragma unroll
            for (int t = 0; t < TAPS; ++t) kst[t] = kr[t * W_ + tid];
        }

        // next h row (enters window at end of this iter)
        f32x4 nxt[4];
        if (yy < 7) {
            const int yn = (yg + 2 < H_) ? (yg + 2) : (H_ - 1);
            #pragma unroll
            for (int i = 0; i < 4; ++i)
                nxt[i] = *(const f32x4*)(hb + i * plane + (size_t)yn * W_ + x0);
        }

        // (b) kt from LDS + fold boundary masks
        f32x4 kt[TAPS];
        #pragma unroll
        for (int t = 0; t < TAPS; ++t) kt[t] = *(const f32x4*)&ksh[cur][t][x0];

        const float m0 = (yg > 0)      ? 1.f : 0.f;
        const float m2 = (yg < H_ - 1) ? 1.f : 0.f;
        #pragma unroll
        for (int t = 0; t < 3; ++t) { kt[t] *= m0; kt[6 + t] *= m2; }
        kt[0].x *= lmask; kt[3].x *= lmask; kt[6].x *= lmask;
        kt[2].w *= rmask; kt[5].w *= rmask; kt[8].w *= rmask;

        // compute 4 channels (pure FMA + 2 shuffles per row)
        float sim[4][4];
        #pragma unroll
        for (int i = 0; i < 4; ++i)
            #pragma unroll
            for (int j = 0; j < 4; ++j) sim[i][j] = 0.f;

        #pragma unroll
        for (int r = 0; r < 3; ++r) {
            const int sl = (yy + r) % 3;          // compile-time after unroll
            const f32x4 k0 = kt[r * 3 + 0];
            const f32x4 k1 = kt[r * 3 + 1];
            const f32x4 k2 = kt[r * 3 + 2];
            #pragma unroll
            for (int i = 0; i < 4; ++i) {
                const f32x4 cv = win[sl][i];
                const float l  = __shfl_up(cv.w, 1);    // x0-1 (lane0 masked via kt)
                const float rr = __shfl_down(cv.x, 1);  // x0+4 (lane63 masked via kt)
                sim[i][0] = fmaf(l,    k0.x, fmaf(cv.x, k1.x, fmaf(cv.y, k2.x, sim[i][0])));
                sim[i][1] = fmaf(cv.x, k0.y, fmaf(cv.y, k1.y, fmaf(cv.z, k2.y, sim[i][1])));
                sim[i][2] = fmaf(cv.y, k0.z, fmaf(cv.z, k1.z, fmaf(cv.w, k2.z, sim[i][2])));
                sim[i][3] = fmaf(cv.z, k0.w, fmaf(cv.w, k1.w, fmaf(rr,   k2.w, sim[i][3])));
            }
        }

        // gate + store
        #pragma unroll
        for (int i = 0; i < 4; ++i) {
            const f32x4 ctr = win[(yy + 1) % 3][i];
            f32x4 o;
            o.x = ctr.x * __builtin_amdgcn_rcpf(1.f + __expf(-sim[i][0]));
            o.y = ctr.y * __builtin_amdgcn_rcpf(1.f + __expf(-sim[i][1]));
            o.z = ctr.z * __builtin_amdgcn_rcpf(1.f + __expf(-sim[i][2]));
            o.w = ctr.w * __builtin_amdgcn_rcpf(1.f + __expf(-sim[i][3]));
            *(f32x4*)(ob + i * plane + (size_t)yg * W_ + x0) = o;
        }

        // rotate h window
        if (yy < 7) {
            #pragma unroll
            for (int i = 0; i < 4; ++i) win[yy % 3][i] = nxt[i];
        }

        // (c) publish next kern row to the alternate LDS buffer, one barrier
        if (yy < 7) {
            #pragma unroll
            for (int t = 0; t < TAPS; ++t) ksh[cur ^ 1][t][tid] = kst[t];
            __syncthreads();
        }
    }
}

// ============================================================================
// Fallback: single fused kernel (used only if ws_size is too small)
// ============================================================================
__global__ __launch_bounds__(256, 4)
void hsa_fused(const float* __restrict__ lr,
               const float* __restrict__ hin,
               const float* __restrict__ w1,
               const float* __restrict__ b1,
               const float* __restrict__ w2,
               const float* __restrict__ b2,
               float* __restrict__ out)
{
    __shared__ float kernS[TAPS][W_];
    __shared__ float w2t[C_][12];

    const int tid = threadIdx.x;
    const int blk = blockIdx.x;
    const int b = blk / H_;
    const int y = blk % H_;

    for (int i = tid; i < TAPS * C_; i += 256) {
        const int t = i / C_;
        const int c = i % C_;
        w2t[c][t] = w2[i];
    }
    __syncthreads();

    {
        const int x = tid;
        float win[CIN][3][3];
        #pragma unroll
        for (int ci = 0; ci < CIN; ++ci)
            #pragma unroll
            for (int r = 0; r < 3; ++r) {
                const int yy = y + r - 1;
                const bool vy = (unsigned)yy < (unsigned)H_;
                const float* row = lr + ((size_t)(b * CIN + ci) * H_ + yy) * W_;
                win[ci][r][0] = (vy && x > 0)      ? row[x - 1] : 0.f;
                win[ci][r][1] = vy                  ? row[x]     : 0.f;
                win[ci][r][2] = (vy && x < W_ - 1) ? row[x + 1] : 0.f;
            }

        float acc[TAPS];
        #pragma unroll
        for (int t = 0; t < TAPS; ++t) acc[t] = b2[t];

        for (int c = 0; c < C_; ++c) {
            const float* wc = w1 + c * 27;
            float h0 = b1[c], h1 = 0.f, h2 = 0.f;
            #pragma unroll
            for (int r = 0; r < 3; ++r)
                #pragma unroll
                for (int j = 0; j < 3; ++j) {
                    h0 = fmaf(wc[(0 * 3 + r) * 3 + j], win[0][r][j], h0);
                    h1 = fmaf(wc[(1 * 3 + r) * 3 + j], win[1][r][j], h1);
                    h2 = fmaf(wc[(2 * 3 + r) * 3 + j], win[2][r][j], h2);
                }
            const float hsum = fmaxf((h0 + h1) + h2, 0.f);
            const float4 wa = *(const float4*)&w2t[c][0];
            const float4 wb = *(const float4*)&w2t[c][4];
            const float  w8 = w2t[c][8];
            acc[0] = fmaf(wa.x, hsum, acc[0]);
            acc[1] = fmaf(wa.y, hsum, acc[1]);
            acc[2] = fmaf(wa.z, hsum, acc[2]);
            acc[3] = fmaf(wa.w, hsum, acc[3]);
            acc[4] = fmaf(wb.x, hsum, acc[4]);
            acc[5] = fmaf(wb.y, hsum, acc[5]);
            acc[6] = fmaf(wb.z, hsum, acc[6]);
            acc[7] = fmaf(wb.w, hsum, acc[7]);
            acc[8] = fmaf(w8,  hsum, acc[8]);
        }
        #pragma unroll
        for (int t = 0; t < TAPS; ++t) kernS[t][x] = acc[t];
    }
    __syncthreads();

    const int lane = tid & 63;
    const int wav  = tid >> 6;
    const int x0   = lane * 4;

    float4 kt[TAPS];
    #pragma unroll
    for (int t = 0; t < TAPS; ++t) kt[t] = *(const float4*)&kernS[t][x0];

    #pragma unroll 4
    for (int cc = 0; cc < 16; ++cc) {
        const int c = wav * 16 + cc;
        const float* hb = hin + (size_t)(b * C_ + c) * H_ * W_;

        float4 rowv[3];
        float  lft[3], rgt[3];
        #pragma unroll
        for (int r = 0; r < 3; ++r) {
            const int yy = y + r - 1;
            const bool vy = (unsigned)yy < (unsigned)H_;
            float4 m;
            if (vy) m = *(const float4*)(hb + (size_t)yy * W_ + x0);
            else    m = make_float4(0.f, 0.f, 0.f, 0.f);
            rowv[r] = m;
            float l  = __shfl_up(m.w, 1);
            float rr = __shfl_down(m.x, 1);
            if (lane == 0)  l  = 0.f;
            if (lane == 63) rr = 0.f;
            lft[r] = l; rgt[r] = rr;
        }

        float sim0 = 0.f, sim1 = 0.f, sim2 = 0.f, sim3 = 0.f;
        #pragma unroll
        for (int r = 0; r < 3; ++r) {
            const float w6_0 = lft[r];
            const float w6_1 = rowv[r].x;
            const float w6_2 = rowv[r].y;
            const float w6_3 = rowv[r].z;
            const float w6_4 = rowv[r].w;
            const float w6_5 = rgt[r];
            { const float4 k4 = kt[r*3+0];
              sim0 = fmaf(w6_0, k4.x, sim0); sim1 = fmaf(w6_1, k4.y, sim1);
              sim2 = fmaf(w6_2, k4.z, sim2); sim3 = fmaf(w6_3, k4.w, sim3); }
            { const float4 k4 = kt[r*3+1];
              sim0 = fmaf(w6_1, k4.x, sim0); sim1 = fmaf(w6_2, k4.y, sim1);
              sim2 = fmaf(w6_3, k4.z, sim2); sim3 = fmaf(w6_4, k4.w, sim3); }
            { const float4 k4 = kt[r*3+2];
              sim0 = fmaf(w6_2, k4.x, sim0); sim1 = fmaf(w6_3, k4.y, sim1);
              sim2 = fmaf(w6_4, k4.z, sim2); sim3 = fmaf(w6_5, k4.w, sim3); }
        }

        float4 o;
        o.x = rowv[1].x * __builtin_amdgcn_rcpf(1.f + __expf(-sim0));
        o.y = rowv[1].y * __builtin_amdgcn_rcpf(1.f + __expf(-sim1));
        o.z = rowv[1].z * __builtin_amdgcn_rcpf(1.f + __expf(-sim2));
        o.w = rowv[1].w * __builtin_amdgcn_rcpf(1.f + __expf(-sim3));
        *(float4*)(out + ((size_t)(b * C_ + c) * H_ + y) * W_ + x0) = o;
    }
}

extern "C" void kernel_launch(void* const* d_in, const int* in_sizes, int n_in,
                              void* d_out, int out_size, void* d_ws, size_t ws_size,
                              hipStream_t stream) {
    const float* lr  = (const float*)d_in[0];  // [8,3,256,256]
    const float* hin = (const float*)d_in[1];  // [8,64,256,256]
    const float* w1  = (const float*)d_in[2];  // [64,3,3,3]
    const float* b1  = (const float*)d_in[3];  // [64]
    const float* w2  = (const float*)d_in[4];  // [9,64,1,1]
    const float* b2  = (const float*)d_in[5];  // [9]
    float* out = (float*)d_out;                // [8,64,256,256]

    const size_t kern_bytes = (size_t)B_ * H_ * TAPS * W_ * sizeof(float);

    if (ws_size >= kern_bytes) {
        float* kws = (float*)d_ws;
        hipLaunchKernelGGL(hsa_kern, dim3(B_ * H_), dim3(256), 0, stream,
                           lr, w1, b1, w2, b2, kws);
        // 8 batches x 32 strips x 4 channel-groups = 1024 blocks
        hipLaunchKernelGGL(hsa_gate, dim3(1024), dim3(256), 0, stream,
                           hin, kws, out);
    } else {
        hipLaunchKernelGGL(hsa_fused, dim3(B_ * H_), dim3(256), 0, stream,
                           lr, hin, w1, b1, w2, b2, out);
    }
}